// Round 1
// baseline (616.494 us; speedup 1.0000x reference)
//
#include <hip/hip_runtime.h>

constexpr int BATCH = 32;
constexpr int HH = 256, WW = 256;
constexpr int NPIX = HH * WW;
constexpr int STEPS = 15;
constexpr float R_C = 3.9f, EPS_C = 0.3f, BETA_C = 0.15f;
constexpr float CLAMP_LO = 1e-4f, CLAMP_HI = 1.0f - 1e-4f;

// ------------------------------------------------------------------ prep
// Fold alpha into Wp2 (w2a = Wp2 * alpha[o]) and fused bias
// bfu[o] = bp1[o] + bp2[o]*alpha[o].  (alpha is a runtime input.)
__global__ void prep_kernel(const float* __restrict__ Wp2,
                            const float* __restrict__ bp1,
                            const float* __restrict__ bp2,
                            const float* __restrict__ alpha,
                            float* __restrict__ w2a,
                            float* __restrict__ bfu) {
  int i = blockIdx.x * 256 + threadIdx.x;
  if (i < 1728) {
    int o = i / 54;
    w2a[i] = Wp2[i] * alpha[o];
  } else if (i < 1760) {
    int o = i - 1728;
    bfu[o] = bp1[o] + bp2[o] * alpha[o];
  }
}

// --------------------------------------------- stencil + online attention
// 15 chaotic-map steps fused in LDS with a 15-deep halo; online softmax over
// the per-pixel trajectory (scores are a'(x)*g_m + const -> softmax-invariant
// const dropped).  Writes `last` and s = sum_m attn_m * g_m.
constexpr int TILE = 64, HALO = 15, REGN = TILE + 2 * HALO;  // 94
constexpr int RS = 96;                                       // LDS row stride
constexpr int T1 = 512;
constexpr int PPT = TILE * TILE / T1;  // 8 interior pixels / thread

__global__ __launch_bounds__(T1) void stencil_kernel(
    const float* __restrict__ x, const float* __restrict__ Kl,
    const float* __restrict__ Wq, const float* __restrict__ bq,
    const float* __restrict__ Wk, float* __restrict__ lastO,
    float* __restrict__ sO) {
  extern __shared__ float lds[];
  float* xb = lds;                 // drive (= original x), region
  float* gb = lds + REGN * RS;     // current state g
  float* mb = lds + 2 * REGN * RS; // mapped = R*g*(1-g), 0 outside image

  const int tx0 = blockIdx.x * TILE, ty0 = blockIdx.y * TILE, b = blockIdx.z;
  const int gx0 = tx0 - HALO, gy0 = ty0 - HALO;
  const int t = threadIdx.x;
  const float* xim = x + (size_t)b * NPIX;

  const float k00 = Kl[0], k01 = Kl[1], k02 = Kl[2];
  const float k10 = Kl[3], k11 = Kl[4], k12 = Kl[5];
  const float k20 = Kl[6], k21 = Kl[7], k22 = Kl[8];

  // score_m = a' * g_m  with  a' = (x*sum(Wq*Wk) + sum(bq*Wk)) / sqrt(3)
  const float swk = Wq[0] * Wk[0] + Wq[1] * Wk[1] + Wq[2] * Wk[2];
  const float sbk = bq[0] * Wk[0] + bq[1] * Wk[1] + bq[2] * Wk[2];
  const float rs3 = 0.57735026918962576f;

  // load region; out-of-image -> 0 (g=0 gives mapped=0 == zero padding,
  // and those pixels are never updated, so they stay exact zeros)
  for (int i = t; i < REGN * REGN; i += T1) {
    int ry = i / REGN, rx = i - ry * REGN;
    int gy = gy0 + ry, gx = gx0 + rx;
    float v = 0.f;
    if (gy >= 0 && gy < HH && gx >= 0 && gx < WW) v = xim[gy * WW + gx];
    xb[ry * RS + rx] = v;
    gb[ry * RS + rx] = v;
  }
  __syncthreads();

  float aq[PPT], se[PPT], wsum[PPT];
#pragma unroll
  for (int k = 0; k < PPT; k++) {
    int idx = k * T1 + t;
    int iy = idx >> 6, ix = idx & 63;
    float xv = xb[(iy + HALO) * RS + (ix + HALO)];
    aq[k] = (xv * swk + sbk) * rs3;
    se[k] = 0.f;
    wsum[k] = 0.f;
  }

  for (int s = 0; s < STEPS; s++) {
    // phase A: mapped (no bounds check needed: out-of-image g stays 0)
    for (int i = t; i < REGN * REGN; i += T1) {
      int ry = i / REGN, rx = i - ry * REGN;
      float g = gb[ry * RS + rx];
      mb[ry * RS + rx] = R_C * g * (1.f - g);
    }
    __syncthreads();
    // phase B: update rows/cols 1..REGN-2 (halo ring validity shrinks 1/step;
    // the interior stays inside the valid cone for all 15 steps)
    for (int i = t; i < (REGN - 2) * (REGN - 2); i += T1) {
      int ry = i / (REGN - 2) + 1, rx = i - (ry - 1) * (REGN - 2) + 1;
      int gy = gy0 + ry, gx = gx0 + rx;
      if (gy >= 0 && gy < HH && gx >= 0 && gx < WW) {
        int o = ry * RS + rx;
        float mc = mb[o];
        float loc = k00 * mb[o - RS - 1] + k01 * mb[o - RS] +
                    k02 * mb[o - RS + 1] + k10 * mb[o - 1] + k11 * mc +
                    k12 * mb[o + 1] + k20 * mb[o + RS - 1] +
                    k21 * mb[o + RS] + k22 * mb[o + RS + 1];
        float ph = (1.f - EPS_C) * mc + EPS_C * loc;
        float g = (1.f - BETA_C) * ph + BETA_C * xb[o];
        g = fminf(fmaxf(g, CLAMP_LO), CLAMP_HI);
        gb[o] = g;
      }
    }
    __syncthreads();
    // phase C: online softmax accumulation for owned interior pixels
#pragma unroll
    for (int k = 0; k < PPT; k++) {
      int idx = k * T1 + t;
      int iy = idx >> 6, ix = idx & 63;
      float g = gb[(iy + HALO) * RS + (ix + HALO)];
      float e = __expf(aq[k] * g);
      se[k] += e;
      wsum[k] += e * g;
    }
    // no barrier needed here: next phase A writes mb (not read in C) and
    // reads gb (read-only in both); B(s+1) is fenced by A's barrier.
  }

#pragma unroll
  for (int k = 0; k < PPT; k++) {
    int idx = k * T1 + t;
    int iy = idx >> 6, ix = idx & 63;
    float g = gb[(iy + HALO) * RS + (ix + HALO)];
    float sv = wsum[k] / se[k];
    size_t gi = (size_t)b * NPIX + (size_t)(ty0 + iy) * WW + (tx0 + ix);
    lastO[gi] = g;
    sO[gi] = sv;
  }
}

// -------------------------------------------------------- conv stack head
// nca channels derived on the fly: [x, last, last-x, Wv[v]*s+bv[v]].
// feat = conv3x3_d1(nca,Wp1)+bp1 + (conv3x3_d2(nca,Wp2)+bp2)*alpha (folded),
// then relu -> 32x32 -> relu -> 32->1 -> last + corr, clip[0,1].
constexpr int CT = 32, CREG = CT + 4, CRS = CREG + 1;  // 36, 37
constexpr int T2 = 256;
constexpr int PPT2 = CT * CT / T2;  // 4

__global__ __launch_bounds__(T2) void conv_kernel(
    const float* __restrict__ x, const float* __restrict__ lastA,
    const float* __restrict__ sA, const float* __restrict__ Wv,
    const float* __restrict__ bv, const float* __restrict__ Wp1,
    const float* __restrict__ w2a, const float* __restrict__ Wu1,
    const float* __restrict__ bu1, const float* __restrict__ Wu2,
    const float* __restrict__ bu2, const float* __restrict__ bfu,
    float* __restrict__ outp) {
  __shared__ __align__(16) float nca[6][CREG][CRS];
  __shared__ __align__(16) float w1L[54 * 32];   // [tap][o]
  __shared__ __align__(16) float w2L[54 * 32];   // [tap][o] (alpha folded)
  __shared__ __align__(16) float wu1L[32 * 32];  // [o'][o]
  __shared__ float bfL[32], bu1L[32], wu2L[32];

  const int cx0 = blockIdx.x * CT, cy0 = blockIdx.y * CT, b = blockIdx.z;
  const int t = threadIdx.x;

  for (int i = t; i < 1728; i += T2) {
    int tap = i >> 5, o = i & 31;
    w1L[i] = Wp1[o * 54 + tap];
    w2L[i] = w2a[o * 54 + tap];
  }
  for (int i = t; i < 1024; i += T2) wu1L[i] = Wu1[i];
  if (t < 32) {
    bfL[t] = bfu[t];
    bu1L[t] = bu1[t];
    wu2L[t] = Wu2[t];
  }

  const float wv0 = Wv[0], wv1 = Wv[1], wv2 = Wv[2];
  const float bv0 = bv[0], bv1 = bv[1], bv2 = bv[2];
  const float bu2v = bu2[0];

  // stage derived channels; out-of-image => ALL channels 0 (zero padding of
  // nca_input, NOT affine-of-zero -- bv must not leak into the pad)
  for (int i = t; i < CREG * CREG; i += T2) {
    int ry = i / CREG, rx = i - ry * CREG;
    int gy = cy0 - 2 + ry, gx = cx0 - 2 + rx;
    float c0 = 0.f, c1 = 0.f, c2 = 0.f, c3 = 0.f, c4 = 0.f, c5 = 0.f;
    if (gy >= 0 && gy < HH && gx >= 0 && gx < WW) {
      size_t gi = (size_t)b * NPIX + (size_t)gy * WW + gx;
      float xv = x[gi], lv = lastA[gi], sv = sA[gi];
      c0 = xv;
      c1 = lv;
      c2 = lv - xv;
      c3 = wv0 * sv + bv0;
      c4 = wv1 * sv + bv1;
      c5 = wv2 * sv + bv2;
    }
    nca[0][ry][rx] = c0;
    nca[1][ry][rx] = c1;
    nca[2][ry][rx] = c2;
    nca[3][ry][rx] = c3;
    nca[4][ry][rx] = c4;
    nca[5][ry][rx] = c5;
  }
  __syncthreads();

  for (int k = 0; k < PPT2; k++) {
    int idx = k * T2 + t;
    int py = idx >> 5, px = idx & 31;
    float acc[32];
#pragma unroll
    for (int o = 0; o < 32; o++) acc[o] = bfL[o];
    for (int c = 0; c < 6; c++) {
#pragma unroll
      for (int ky = 0; ky < 3; ky++) {
#pragma unroll
        for (int kx = 0; kx < 3; kx++) {
          float v1 = nca[c][py + 1 + ky][px + 1 + kx];     // dilation 1
          float v2 = nca[c][py + 2 * ky][px + 2 * kx];     // dilation 2
          int tap = c * 9 + ky * 3 + kx;
          const float4* w1p = (const float4*)&w1L[tap * 32];
          const float4* w2p = (const float4*)&w2L[tap * 32];
#pragma unroll
          for (int q = 0; q < 8; q++) {
            float4 wa = w1p[q], wb = w2p[q];
            acc[q * 4 + 0] += wa.x * v1 + wb.x * v2;
            acc[q * 4 + 1] += wa.y * v1 + wb.y * v2;
            acc[q * 4 + 2] += wa.z * v1 + wb.z * v2;
            acc[q * 4 + 3] += wa.w * v1 + wb.w * v2;
          }
        }
      }
    }
#pragma unroll
    for (int o = 0; o < 32; o++) acc[o] = fmaxf(acc[o], 0.f);
    float corr = 0.f;
    for (int op = 0; op < 32; op++) {
      const float4* wp = (const float4*)&wu1L[op * 32];
      float h = bu1L[op];
#pragma unroll
      for (int q = 0; q < 8; q++) {
        float4 w = wp[q];
        h += w.x * acc[q * 4 + 0] + w.y * acc[q * 4 + 1] +
             w.z * acc[q * 4 + 2] + w.w * acc[q * 4 + 3];
      }
      corr += wu2L[op] * fmaxf(h, 0.f);
    }
    float lastc = nca[1][py + 2][px + 2];
    float ov = lastc + bu2v + corr;
    ov = fminf(fmaxf(ov, 0.f), 1.f);
    outp[(size_t)b * NPIX + (size_t)(cy0 + py) * WW + (cx0 + px)] = ov;
  }
}

extern "C" void kernel_launch(void* const* d_in, const int* in_sizes, int n_in,
                              void* d_out, int out_size, void* d_ws,
                              size_t ws_size, hipStream_t stream) {
  const float* x = (const float*)d_in[0];
  const float* Kl = (const float*)d_in[1];
  const float* Wq = (const float*)d_in[2];
  const float* bq = (const float*)d_in[3];
  const float* Wk = (const float*)d_in[4];
  // d_in[5] = bk: unused (adds an m-invariant constant to scores -> softmax
  // invariant)
  const float* Wv = (const float*)d_in[6];
  const float* bv = (const float*)d_in[7];
  const float* Wp1 = (const float*)d_in[8];
  const float* bp1 = (const float*)d_in[9];
  const float* Wp2 = (const float*)d_in[10];
  const float* bp2 = (const float*)d_in[11];
  const float* alpha = (const float*)d_in[12];
  const float* Wu1 = (const float*)d_in[13];
  const float* bu1 = (const float*)d_in[14];
  const float* Wu2 = (const float*)d_in[15];
  const float* bu2 = (const float*)d_in[16];
  float* outp = (float*)d_out;

  float* ws = (float*)d_ws;
  float* lastA = ws;                            // 32*65536 floats
  float* sA = ws + (size_t)BATCH * NPIX;        // 32*65536 floats
  float* w2a = ws + 2 * (size_t)BATCH * NPIX;   // 1728 floats
  float* bfu = w2a + 1728;                      // 32 floats

  prep_kernel<<<7, 256, 0, stream>>>(Wp2, bp1, bp2, alpha, w2a, bfu);

  dim3 g1(WW / TILE, HH / TILE, BATCH);
  size_t lds1 = (size_t)3 * REGN * RS * sizeof(float);  // ~106 KB
  stencil_kernel<<<g1, T1, lds1, stream>>>(x, Kl, Wq, bq, Wk, lastA, sA);

  dim3 g2(WW / CT, HH / CT, BATCH);
  conv_kernel<<<g2, T2, 0, stream>>>(x, lastA, sA, Wv, bv, Wp1, w2a, Wu1, bu1,
                                     Wu2, bu2, bfu, outp);
}

// Round 2
// 213.628 us; speedup vs baseline: 2.8858x; 2.8858x over previous
//
#include <hip/hip_runtime.h>

constexpr int BATCH = 32;
constexpr int HH = 256, WW = 256;
constexpr int NPIX = HH * WW;
constexpr int STEPS = 15;
constexpr float R_C = 3.9f, EPS_C = 0.3f, BETA_C = 0.15f;
constexpr float CLAMP_LO = 1e-4f, CLAMP_HI = 1.0f - 1e-4f;

typedef __attribute__((ext_vector_type(8))) short short8;
typedef __attribute__((ext_vector_type(4))) float f32x4;

__device__ inline unsigned short f2bf(float f) {
  unsigned int u = __float_as_uint(f);
  return (unsigned short)((u + 0x7fffu + ((u >> 16) & 1u)) >> 16);
}

// Virtual-tap tables: 18 real taps (9 d1 + 9 d2) + 2 zero pads, permuted so
// each K-step's 4 lane-groups hit distinct LDS bank phases
// ((5*oy+ox) mod 8 distinct within each group of 4).
// oy/ox are region offsets relative to pixel (py,px) with halo 2:
//   d1 tap (ky,kx) -> (1+ky, 1+kx);  d2 tap (ky,kx) -> (2ky, 2kx).
__constant__ int VT_OY[20] = {1,2,3,1, 3,0,0,2, 0,2,2,4, 4,4,3,2, 0,0,2,1};
__constant__ int VT_OX[20] = {3,2,3,1, 1,4,2,4, 0,2,0,2, 4,0,2,1, 1,3,3,2};
__constant__ int VT_SRC[20]= {0,0,0,0, 0,1,1,1, 1,1,1,1, 1,1,0,0, 2,2,0,0};
__constant__ int VT_TAP[20]= {2,4,8,0, 6,2,1,5, 0,4,3,7, 8,6,7,3, 0,0,5,1};

// ------------------------------------------------------------------ prep
// Pack conv weights (alpha folded into d2) into A-fragment layout:
// apack[((t*2+mt)*64 + lane)*8 + j] = W(o=(lane&15)+16mt, vt=4t+(lane>>4), c=j)
// u1pack[(mt*64+lane)*8 + j] = Wu1[(lane&15)+16mt][8*(lane>>4)+j]
// bfu[o] = bp1[o] + bp2[o]*alpha[o]
__global__ void prep_kernel(const float* __restrict__ Wp1,
                            const float* __restrict__ Wp2,
                            const float* __restrict__ bp1,
                            const float* __restrict__ bp2,
                            const float* __restrict__ alpha,
                            const float* __restrict__ Wu1,
                            unsigned short* __restrict__ apack,
                            unsigned short* __restrict__ u1pack,
                            float* __restrict__ bfu) {
  int i = blockIdx.x * 256 + threadIdx.x;
  if (i < 5120) {
    int j = i & 7, lane = (i >> 3) & 63, tm = i >> 9;
    int mt = tm & 1;
    int o = (lane & 15) + 16 * mt, g = lane >> 4, vt = (tm >> 1) * 4 + g;
    float w = 0.f;
    if (j < 6 && VT_SRC[vt] != 2) {
      int base = o * 54 + j * 9 + VT_TAP[vt];
      w = (VT_SRC[vt] == 0) ? Wp1[base] : Wp2[base] * alpha[o];
    }
    apack[i] = f2bf(w);
  } else if (i < 6144) {
    int i2 = i - 5120;
    int j = i2 & 7, lane = (i2 >> 3) & 63, mt = i2 >> 9;
    int o = (lane & 15) + 16 * mt, g = lane >> 4;
    u1pack[i2] = f2bf(Wu1[o * 32 + 8 * g + j]);
  } else if (i < 6176) {
    int o = i - 6144;
    bfu[o] = bp1[o] + bp2[o] * alpha[o];
  }
}

// --------------------------------------------- stencil + online attention
constexpr int TILE = 64, HALO = 15, REGN = TILE + 2 * HALO;  // 94
constexpr int RS = 96;
constexpr int T1 = 512;
constexpr int PPT = TILE * TILE / T1;  // 8

__global__ __launch_bounds__(T1) void stencil_kernel(
    const float* __restrict__ x, const float* __restrict__ Kl,
    const float* __restrict__ Wq, const float* __restrict__ bq,
    const float* __restrict__ Wk, float* __restrict__ lastO,
    float* __restrict__ sO) {
  extern __shared__ float lds[];
  float* xb = lds;
  float* gb = lds + REGN * RS;
  float* mb = lds + 2 * REGN * RS;

  const int tx0 = blockIdx.x * TILE, ty0 = blockIdx.y * TILE, b = blockIdx.z;
  const int gx0 = tx0 - HALO, gy0 = ty0 - HALO;
  const int t = threadIdx.x;
  const float* xim = x + (size_t)b * NPIX;

  const float k00 = Kl[0], k01 = Kl[1], k02 = Kl[2];
  const float k10 = Kl[3], k11 = Kl[4], k12 = Kl[5];
  const float k20 = Kl[6], k21 = Kl[7], k22 = Kl[8];

  const float swk = Wq[0] * Wk[0] + Wq[1] * Wk[1] + Wq[2] * Wk[2];
  const float sbk = bq[0] * Wk[0] + bq[1] * Wk[1] + bq[2] * Wk[2];
  const float rs3 = 0.57735026918962576f;

  for (int i = t; i < REGN * REGN; i += T1) {
    int ry = i / REGN, rx = i - ry * REGN;
    int gy = gy0 + ry, gx = gx0 + rx;
    float v = 0.f;
    if (gy >= 0 && gy < HH && gx >= 0 && gx < WW) v = xim[gy * WW + gx];
    xb[ry * RS + rx] = v;
    gb[ry * RS + rx] = v;
  }
  __syncthreads();

  float aq[PPT], se[PPT], wsum[PPT];
#pragma unroll
  for (int k = 0; k < PPT; k++) {
    int idx = k * T1 + t;
    int iy = idx >> 6, ix = idx & 63;
    float xv = xb[(iy + HALO) * RS + (ix + HALO)];
    aq[k] = (xv * swk + sbk) * rs3;
    se[k] = 0.f;
    wsum[k] = 0.f;
  }

  for (int s = 0; s < STEPS; s++) {
    for (int i = t; i < REGN * REGN; i += T1) {
      int ry = i / REGN, rx = i - ry * REGN;
      float g = gb[ry * RS + rx];
      mb[ry * RS + rx] = R_C * g * (1.f - g);
    }
    __syncthreads();
    for (int i = t; i < (REGN - 2) * (REGN - 2); i += T1) {
      int ry = i / (REGN - 2) + 1, rx = i - (ry - 1) * (REGN - 2) + 1;
      int gy = gy0 + ry, gx = gx0 + rx;
      if (gy >= 0 && gy < HH && gx >= 0 && gx < WW) {
        int o = ry * RS + rx;
        float mc = mb[o];
        float loc = k00 * mb[o - RS - 1] + k01 * mb[o - RS] +
                    k02 * mb[o - RS + 1] + k10 * mb[o - 1] + k11 * mc +
                    k12 * mb[o + 1] + k20 * mb[o + RS - 1] +
                    k21 * mb[o + RS] + k22 * mb[o + RS + 1];
        float ph = (1.f - EPS_C) * mc + EPS_C * loc;
        float g = (1.f - BETA_C) * ph + BETA_C * xb[o];
        g = fminf(fmaxf(g, CLAMP_LO), CLAMP_HI);
        gb[o] = g;
      }
    }
    __syncthreads();
#pragma unroll
    for (int k = 0; k < PPT; k++) {
      int idx = k * T1 + t;
      int iy = idx >> 6, ix = idx & 63;
      float g = gb[(iy + HALO) * RS + (ix + HALO)];
      float e = __expf(aq[k] * g);
      se[k] += e;
      wsum[k] += e * g;
    }
  }

#pragma unroll
  for (int k = 0; k < PPT; k++) {
    int idx = k * T1 + t;
    int iy = idx >> 6, ix = idx & 63;
    float g = gb[(iy + HALO) * RS + (ix + HALO)];
    float sv = wsum[k] / se[k];
    size_t gi = (size_t)b * NPIX + (size_t)(ty0 + iy) * WW + (tx0 + ix);
    lastO[gi] = g;
    sO[gi] = sv;
  }
}

// ------------------------------------------------- conv stack via MFMA
// Tile 32x32 pixels, 4 waves (8 rows each, 2 nfrags/row of 16 pixels).
// nca tile in LDS: [36 rows][37 chunk stride][8 ch] bf16 (halo 2).
// conv: 5 K-steps x 2 M-tiles of mfma_f32_16x16x32_bf16; B-frag = one
// ds_read_b128 per lane.  MLP: LDS round-trip + 2 MFMAs + shfl reduce.
constexpr int CT = 32;
constexpr int NR = 36, NCS = 37;  // region rows, chunk row stride
constexpr int T2 = 256;

__global__ __launch_bounds__(T2) void conv_kernel(
    const float* __restrict__ x, const float* __restrict__ lastA,
    const float* __restrict__ sA, const float* __restrict__ Wv,
    const float* __restrict__ bv, const unsigned short* __restrict__ apackG,
    const unsigned short* __restrict__ u1packG,
    const float* __restrict__ bfuG, const float* __restrict__ bu1G,
    const float* __restrict__ Wu2G, const float* __restrict__ bu2G,
    float* __restrict__ outp) {
  __shared__ __align__(16) unsigned short ncaL[NR * NCS * 8];  // 21312 B
  __shared__ __align__(16) unsigned short featL[4 * 16 * 40];  // 5120 B
  __shared__ __align__(16) float outL[CT * CT];                // 4096 B

  const int cx0 = blockIdx.x * CT, cy0 = blockIdx.y * CT, b = blockIdx.z;
  const int t = threadIdx.x;
  const int w = t >> 6, lane = t & 63;
  const int g = lane >> 4, col = lane & 15;

  // ---- stage nca region as bf16 [y][x][8ch]
  const float wv0 = Wv[0], wv1 = Wv[1], wv2 = Wv[2];
  const float bv0 = bv[0], bv1 = bv[1], bv2 = bv[2];
  for (int i = t; i < NR * NR; i += T2) {
    int ry = i / NR, rx = i - ry * NR;
    int gy = cy0 - 2 + ry, gx = cx0 - 2 + rx;
    unsigned short c[8];
    if (gy >= 0 && gy < HH && gx >= 0 && gx < WW) {
      size_t gi = (size_t)b * NPIX + (size_t)gy * WW + gx;
      float xv = x[gi], lv = lastA[gi], sv = sA[gi];
      c[0] = f2bf(xv);
      c[1] = f2bf(lv);
      c[2] = f2bf(lv - xv);
      c[3] = f2bf(wv0 * sv + bv0);
      c[4] = f2bf(wv1 * sv + bv1);
      c[5] = f2bf(wv2 * sv + bv2);
    } else {
      c[0] = c[1] = c[2] = c[3] = c[4] = c[5] = 0;
    }
    c[6] = c[7] = 0;
    short8 v;
    v[0] = (short)c[0]; v[1] = (short)c[1]; v[2] = (short)c[2];
    v[3] = (short)c[3]; v[4] = (short)c[4]; v[5] = (short)c[5];
    v[6] = 0; v[7] = 0;
    *(short8*)&ncaL[(ry * NCS + rx) * 8] = v;
  }

  // ---- per-lane constants (overlap with staging latency)
  const short8* ap = (const short8*)apackG;
  short8 wfr[10];
#pragma unroll
  for (int q = 0; q < 10; q++) wfr[q] = ap[q * 64 + lane];
  const short8* up = (const short8*)u1packG;
  short8 u1fr[2];
  u1fr[0] = up[lane];
  u1fr[1] = up[64 + lane];

  float bf0[4], bf1[4], bu1a[4], bu1b[4], wu2a[4], wu2b[4];
#pragma unroll
  for (int r = 0; r < 4; r++) {
    bf0[r] = bfuG[4 * g + r];
    bf1[r] = bfuG[16 + 4 * g + r];
    bu1a[r] = bu1G[4 * g + r];
    bu1b[r] = bu1G[16 + 4 * g + r];
    wu2a[r] = Wu2G[4 * g + r];
    wu2b[r] = Wu2G[16 + 4 * g + r];
  }
  const float bu2v = bu2G[0];

  int bofft[5];
#pragma unroll
  for (int tt = 0; tt < 5; tt++) {
    int vt = 4 * tt + g;
    bofft[tt] = VT_OY[vt] * NCS + VT_OX[vt];
  }

  __syncthreads();

  unsigned short* fw = &featL[w * 640];  // 16 pix x 40 ch per wave
  const f32x4 zacc = {0.f, 0.f, 0.f, 0.f};

  for (int rr = 0; rr < 8; rr++) {
    int py = 8 * w + rr;
#pragma unroll
    for (int half = 0; half < 2; half++) {
      int px0 = 16 * half;
      int cbase = py * NCS + px0 + col;
      f32x4 a0 = zacc, a1 = zacc;
#pragma unroll
      for (int tt = 0; tt < 5; tt++) {
        short8 bf = *(const short8*)&ncaL[(cbase + bofft[tt]) * 8];
        a0 = __builtin_amdgcn_mfma_f32_16x16x32_bf16(wfr[2 * tt], bf, a0, 0, 0, 0);
        a1 = __builtin_amdgcn_mfma_f32_16x16x32_bf16(wfr[2 * tt + 1], bf, a1, 0, 0, 0);
      }
      // feat -> relu -> bf16 -> per-wave LDS scratch
      unsigned p00, p01, p10, p11;
      {
        float f0 = fmaxf(a0[0] + bf0[0], 0.f), f1 = fmaxf(a0[1] + bf0[1], 0.f);
        float f2 = fmaxf(a0[2] + bf0[2], 0.f), f3 = fmaxf(a0[3] + bf0[3], 0.f);
        p00 = (unsigned)f2bf(f0) | ((unsigned)f2bf(f1) << 16);
        p01 = (unsigned)f2bf(f2) | ((unsigned)f2bf(f3) << 16);
        float h0 = fmaxf(a1[0] + bf1[0], 0.f), h1 = fmaxf(a1[1] + bf1[1], 0.f);
        float h2 = fmaxf(a1[2] + bf1[2], 0.f), h3 = fmaxf(a1[3] + bf1[3], 0.f);
        p10 = (unsigned)f2bf(h0) | ((unsigned)f2bf(h1) << 16);
        p11 = (unsigned)f2bf(h2) | ((unsigned)f2bf(h3) << 16);
      }
      uint2 wv_a; wv_a.x = p00; wv_a.y = p01;
      uint2 wv_b; wv_b.x = p10; wv_b.y = p11;
      *(uint2*)&fw[col * 40 + 4 * g] = wv_a;        // ch 4g..4g+3
      *(uint2*)&fw[col * 40 + 16 + 4 * g] = wv_b;   // ch 16+4g..
      short8 pf = *(const short8*)&fw[col * 40 + 8 * g];
      f32x4 hA = __builtin_amdgcn_mfma_f32_16x16x32_bf16(u1fr[0], pf, zacc, 0, 0, 0);
      f32x4 hB = __builtin_amdgcn_mfma_f32_16x16x32_bf16(u1fr[1], pf, zacc, 0, 0, 0);
      float cp = 0.f;
#pragma unroll
      for (int r = 0; r < 4; r++) {
        cp += wu2a[r] * fmaxf(hA[r] + bu1a[r], 0.f);
        cp += wu2b[r] * fmaxf(hB[r] + bu1b[r], 0.f);
      }
      cp += __shfl_xor(cp, 16);
      cp += __shfl_xor(cp, 32);
      float lastv = lastA[(size_t)b * NPIX + (size_t)(cy0 + py) * WW +
                          (cx0 + px0 + col)];
      float ov = fminf(fmaxf(lastv + bu2v + cp, 0.f), 1.f);
      if (lane < 16) outL[py * CT + px0 + col] = ov;
    }
  }

  // ---- coalesced store (wave-local rows: no barrier needed)
  float4 o4 = *(float4*)&outL[t * 4];
  int row = (t * 4) >> 5, colf = (t * 4) & 31;
  *(float4*)&outp[(size_t)b * NPIX + (size_t)(cy0 + row) * WW + cx0 + colf] = o4;
}

extern "C" void kernel_launch(void* const* d_in, const int* in_sizes, int n_in,
                              void* d_out, int out_size, void* d_ws,
                              size_t ws_size, hipStream_t stream) {
  const float* x = (const float*)d_in[0];
  const float* Kl = (const float*)d_in[1];
  const float* Wq = (const float*)d_in[2];
  const float* bq = (const float*)d_in[3];
  const float* Wk = (const float*)d_in[4];
  // d_in[5] = bk: softmax-invariant, unused
  const float* Wv = (const float*)d_in[6];
  const float* bv = (const float*)d_in[7];
  const float* Wp1 = (const float*)d_in[8];
  const float* bp1 = (const float*)d_in[9];
  const float* Wp2 = (const float*)d_in[10];
  const float* bp2 = (const float*)d_in[11];
  const float* alpha = (const float*)d_in[12];
  const float* Wu1 = (const float*)d_in[13];
  const float* bu1 = (const float*)d_in[14];
  const float* Wu2 = (const float*)d_in[15];
  const float* bu2 = (const float*)d_in[16];
  float* outp = (float*)d_out;

  float* ws = (float*)d_ws;
  float* lastA = ws;
  float* sA = ws + (size_t)BATCH * NPIX;
  unsigned short* apack = (unsigned short*)(ws + 2 * (size_t)BATCH * NPIX);
  unsigned short* u1pack = apack + 5120;
  float* bfu = (float*)(u1pack + 1024);

  prep_kernel<<<25, 256, 0, stream>>>(Wp1, Wp2, bp1, bp2, alpha, Wu1, apack,
                                      u1pack, bfu);

  dim3 g1(WW / TILE, HH / TILE, BATCH);
  size_t lds1 = (size_t)3 * REGN * RS * sizeof(float);
  stencil_kernel<<<g1, T1, lds1, stream>>>(x, Kl, Wq, bq, Wk, lastA, sA);

  dim3 g2(WW / CT, HH / CT, BATCH);
  conv_kernel<<<g2, T2, 0, stream>>>(x, lastA, sA, Wv, bv, apack, u1pack, bfu,
                                     bu1, Wu2, bu2, outp);
}

// Round 3
// 182.852 us; speedup vs baseline: 3.3715x; 1.1683x over previous
//
#include <hip/hip_runtime.h>

constexpr int BATCH = 32;
constexpr int HH = 256, WW = 256;
constexpr int NPIX = HH * WW;
constexpr int STEPS = 15;
constexpr float R_C = 3.9f, EPS_C = 0.3f, BETA_C = 0.15f;
constexpr float CLAMP_LO = 1e-4f, CLAMP_HI = 1.0f - 1e-4f;

typedef __attribute__((ext_vector_type(8))) short short8;
typedef __attribute__((ext_vector_type(4))) float f32x4;

__device__ inline unsigned short f2bf(float f) {
  unsigned int u = __float_as_uint(f);
  return (unsigned short)((u + 0x7fffu + ((u >> 16) & 1u)) >> 16);
}

// Virtual-tap tables (conv): 18 real taps (9 d1 + 9 d2) + 2 zero pads,
// permuted for LDS bank phase diversity.
__constant__ int VT_OY[20] = {1,2,3,1, 3,0,0,2, 0,2,2,4, 4,4,3,2, 0,0,2,1};
__constant__ int VT_OX[20] = {3,2,3,1, 1,4,2,4, 0,2,0,2, 4,0,2,1, 1,3,3,2};
__constant__ int VT_SRC[20]= {0,0,0,0, 0,1,1,1, 1,1,1,1, 1,1,0,0, 2,2,0,0};
__constant__ int VT_TAP[20]= {2,4,8,0, 6,2,1,5, 0,4,3,7, 8,6,7,3, 0,0,5,1};

// ------------------------------------------------------------------ prep
__global__ void prep_kernel(const float* __restrict__ Wp1,
                            const float* __restrict__ Wp2,
                            const float* __restrict__ bp1,
                            const float* __restrict__ bp2,
                            const float* __restrict__ alpha,
                            const float* __restrict__ Wu1,
                            unsigned short* __restrict__ apack,
                            unsigned short* __restrict__ u1pack,
                            float* __restrict__ bfu) {
  int i = blockIdx.x * 256 + threadIdx.x;
  if (i < 5120) {
    int j = i & 7, lane = (i >> 3) & 63, tm = i >> 9;
    int mt = tm & 1;
    int o = (lane & 15) + 16 * mt, g = lane >> 4, vt = (tm >> 1) * 4 + g;
    float w = 0.f;
    if (j < 6 && VT_SRC[vt] != 2) {
      int base = o * 54 + j * 9 + VT_TAP[vt];
      w = (VT_SRC[vt] == 0) ? Wp1[base] : Wp2[base] * alpha[o];
    }
    apack[i] = f2bf(w);
  } else if (i < 6144) {
    int i2 = i - 5120;
    int j = i2 & 7, lane = (i2 >> 3) & 63, mt = i2 >> 9;
    int o = (lane & 15) + 16 * mt, g = lane >> 4;
    u1pack[i2] = f2bf(Wu1[o * 32 + 8 * g + j]);
  } else if (i < 6176) {
    int o = i - 6144;
    bfu[o] = bp1[o] + bp2[o] * alpha[o];
  }
}

// --------------------------------------------- stencil + online attention
// Register-strip design: thread owns a 4w x 6h strip of the 96^2 region
// (tile 64^2, halo 15, region rows/cols 0..95, tile = region [15,78]^2).
// g/x/softmax-accum in VGPRs; LDS holds only `mapped` (1 buffer, 40KB).
// Per step: write own mapped (b128) -> bar -> sliding-window b128 reads ->
// update g (predicated by shrinking cone [s+1,94-s] folded with image
// bounds, so out-of-image g stays exactly 0 = zero padding) -> bar.
constexpr int T1 = 384;        // 24 strips across x 16 strip-rows
constexpr int LSTR = 104;      // LDS row stride (words): 4-col pad L+R

#define WE(W, i) (W[(i) >> 2][(i) & 3])
#define LDROW(dst, rw) {                                        \
    const f32x4* p_ = (const f32x4*)&mlds[(rw) * LSTR + c0];    \
    dst[0] = p_[0]; dst[1] = p_[1]; dst[2] = p_[2]; }
#define STROW(rr_, WT, WM, WB) {                                          \
    int rn_ = r0 + (rr_) + 1;                                             \
    LDROW(WB, (rn_ < 96 ? rn_ : 95));                                     \
    const int ry_ = r0 + (rr_);                                           \
    const bool rowok_ = (ry_ >= rlo) && (ry_ <= rhi);                     \
    _Pragma("unroll")                                                     \
    for (int c = 0; c < 4; c++) {                                         \
      float mc = WE(WM, 4 + c);                                           \
      float loc = k00 * WE(WT, 3 + c) + k01 * WE(WT, 4 + c) +             \
                  k02 * WE(WT, 5 + c) + k10 * WE(WM, 3 + c) + k11 * mc +  \
                  k12 * WE(WM, 5 + c) + k20 * WE(WB, 3 + c) +             \
                  k21 * WE(WB, 4 + c) + k22 * WE(WB, 5 + c);              \
      float ph = (1.f - EPS_C) * mc + EPS_C * loc;                        \
      float gn = (1.f - BETA_C) * ph + BETA_C * xr[rr_][c];               \
      gn = fminf(fmaxf(gn, CLAMP_LO), CLAMP_HI);                          \
      bool upd = rowok_ && (c0 + c >= clo) && (c0 + c <= chi);            \
      g[rr_][c] = upd ? gn : g[rr_][c];                                   \
    } }

__global__ __launch_bounds__(T1, 3) void stencil_kernel(
    const float* __restrict__ x, const float* __restrict__ Kl,
    const float* __restrict__ Wq, const float* __restrict__ bq,
    const float* __restrict__ Wk, float* __restrict__ lastO,
    float* __restrict__ sO) {
  __shared__ float mlds[96 * LSTR];  // 39,936 B

  const int tx0 = blockIdx.x * 64, ty0 = blockIdx.y * 64, b = blockIdx.z;
  const int gx0 = tx0 - 15, gy0 = ty0 - 15;
  const int t = threadIdx.x;
  const int sx = t % 24, sy = t / 24;
  const int c0 = 4 * sx, r0 = 6 * sy;
  const float* xim = x + (size_t)b * NPIX;

  const float k00 = Kl[0], k01 = Kl[1], k02 = Kl[2];
  const float k10 = Kl[3], k11 = Kl[4], k12 = Kl[5];
  const float k20 = Kl[6], k21 = Kl[7], k22 = Kl[8];

  const float swk = Wq[0] * Wk[0] + Wq[1] * Wk[1] + Wq[2] * Wk[2];
  const float sbk = bq[0] * Wk[0] + bq[1] * Wk[1] + bq[2] * Wk[2];
  const float rs3 = 0.57735026918962576f;
  const float a1 = swk * rs3, a0c = sbk * rs3;  // score = (a1*x + a0c)*g

  // image-validity folded bounds (region coords); uniform per block
  const int rlo_img = (0 > -gy0) ? 0 : -gy0;
  const int rhi_img = (95 < 255 - gy0) ? 95 : 255 - gy0;
  const int clo_img = (0 > -gx0) ? 0 : -gx0;
  const int chi_img = (95 < 255 - gx0) ? 95 : 255 - gx0;

  float xr[6][4], g[6][4], se[6][4], wsum[6][4];
#pragma unroll
  for (int r = 0; r < 6; r++) {
    int gy = gy0 + r0 + r;
    bool rin = (unsigned)gy < 256u;
#pragma unroll
    for (int c = 0; c < 4; c++) {
      int gx = gx0 + c0 + c;
      float v = 0.f;
      if (rin && (unsigned)gx < 256u) v = xim[gy * WW + gx];
      xr[r][c] = v;
      g[r][c] = v;
      se[r][c] = 0.f;
      wsum[r][c] = 0.f;
    }
  }

  const bool has_tile =
      (r0 + 5 >= 15) && (r0 <= 78) && (c0 + 3 >= 15) && (c0 <= 78);

  for (int s = 0; s < STEPS; s++) {
    // phase 1: mapped -> LDS (stale values outside cone are never read by
    // still-valid pixels; out-of-image g==0 -> mapped==0 == zero padding)
#pragma unroll
    for (int r = 0; r < 6; r++) {
      f32x4 m;
#pragma unroll
      for (int c = 0; c < 4; c++) m[c] = R_C * g[r][c] * (1.f - g[r][c]);
      *(f32x4*)&mlds[(r0 + r) * LSTR + 4 + c0] = m;
    }
    __syncthreads();
    // phase 2: 9-pt stencil from sliding 3-row b128 window, cone-predicated
    const int lo = s + 1, hi = 94 - s;
    const int rlo = (lo > rlo_img) ? lo : rlo_img;
    const int rhi = (hi < rhi_img) ? hi : rhi_img;
    const int clo = (lo > clo_img) ? lo : clo_img;
    const int chi = (hi < chi_img) ? hi : chi_img;
    if (r0 + 5 >= rlo && r0 <= rhi && c0 + 3 >= clo && c0 <= chi) {
      f32x4 w0[3], w1[3], w2[3];
      LDROW(w0, (r0 > 0 ? r0 - 1 : 0));
      LDROW(w1, r0);
      STROW(0, w0, w1, w2);
      STROW(1, w1, w2, w0);
      STROW(2, w2, w0, w1);
      STROW(3, w0, w1, w2);
      STROW(4, w1, w2, w0);
      STROW(5, w2, w0, w1);
    }
    // phase 3: online softmax accumulate (only strips holding tile pixels)
    if (has_tile) {
#pragma unroll
      for (int r = 0; r < 6; r++)
#pragma unroll
        for (int c = 0; c < 4; c++) {
          float gv = g[r][c];
          float e = __expf((a1 * xr[r][c] + a0c) * gv);
          se[r][c] += e;
          wsum[r][c] = fmaf(e, gv, wsum[r][c]);
        }
    }
    __syncthreads();
  }

  if (has_tile) {
#pragma unroll
    for (int r = 0; r < 6; r++) {
      int ry = r0 + r;
      if (ry < 15 || ry > 78) continue;
      int gy = ty0 + ry - 15;
#pragma unroll
      for (int c = 0; c < 4; c++) {
        int rx = c0 + c;
        if (rx < 15 || rx > 78) continue;
        int gx = tx0 + rx - 15;
        size_t gi = (size_t)b * NPIX + (size_t)gy * WW + gx;
        lastO[gi] = g[r][c];
        sO[gi] = wsum[r][c] / se[r][c];
      }
    }
  }
}

// ------------------------------------------------- conv stack via MFMA
constexpr int CT = 32;
constexpr int NR = 36, NCS = 37;
constexpr int T2 = 256;

__global__ __launch_bounds__(T2) void conv_kernel(
    const float* __restrict__ x, const float* __restrict__ lastA,
    const float* __restrict__ sA, const float* __restrict__ Wv,
    const float* __restrict__ bv, const unsigned short* __restrict__ apackG,
    const unsigned short* __restrict__ u1packG,
    const float* __restrict__ bfuG, const float* __restrict__ bu1G,
    const float* __restrict__ Wu2G, const float* __restrict__ bu2G,
    float* __restrict__ outp) {
  __shared__ __align__(16) unsigned short ncaL[NR * NCS * 8];
  __shared__ __align__(16) unsigned short featL[4 * 16 * 40];
  __shared__ __align__(16) float outL[CT * CT];

  const int cx0 = blockIdx.x * CT, cy0 = blockIdx.y * CT, b = blockIdx.z;
  const int t = threadIdx.x;
  const int w = t >> 6, lane = t & 63;
  const int g = lane >> 4, col = lane & 15;

  const float wv0 = Wv[0], wv1 = Wv[1], wv2 = Wv[2];
  const float bv0 = bv[0], bv1 = bv[1], bv2 = bv[2];
  for (int i = t; i < NR * NR; i += T2) {
    int ry = i / NR, rx = i - ry * NR;
    int gy = cy0 - 2 + ry, gx = cx0 - 2 + rx;
    unsigned short c[8];
    if (gy >= 0 && gy < HH && gx >= 0 && gx < WW) {
      size_t gi = (size_t)b * NPIX + (size_t)gy * WW + gx;
      float xv = x[gi], lv = lastA[gi], sv = sA[gi];
      c[0] = f2bf(xv);
      c[1] = f2bf(lv);
      c[2] = f2bf(lv - xv);
      c[3] = f2bf(wv0 * sv + bv0);
      c[4] = f2bf(wv1 * sv + bv1);
      c[5] = f2bf(wv2 * sv + bv2);
    } else {
      c[0] = c[1] = c[2] = c[3] = c[4] = c[5] = 0;
    }
    short8 v;
    v[0] = (short)c[0]; v[1] = (short)c[1]; v[2] = (short)c[2];
    v[3] = (short)c[3]; v[4] = (short)c[4]; v[5] = (short)c[5];
    v[6] = 0; v[7] = 0;
    *(short8*)&ncaL[(ry * NCS + rx) * 8] = v;
  }

  const short8* ap = (const short8*)apackG;
  short8 wfr[10];
#pragma unroll
  for (int q = 0; q < 10; q++) wfr[q] = ap[q * 64 + lane];
  const short8* up = (const short8*)u1packG;
  short8 u1fr[2];
  u1fr[0] = up[lane];
  u1fr[1] = up[64 + lane];

  float bf0[4], bf1[4], bu1a[4], bu1b[4], wu2a[4], wu2b[4];
#pragma unroll
  for (int r = 0; r < 4; r++) {
    bf0[r] = bfuG[4 * g + r];
    bf1[r] = bfuG[16 + 4 * g + r];
    bu1a[r] = bu1G[4 * g + r];
    bu1b[r] = bu1G[16 + 4 * g + r];
    wu2a[r] = Wu2G[4 * g + r];
    wu2b[r] = Wu2G[16 + 4 * g + r];
  }
  const float bu2v = bu2G[0];

  int bofft[5];
#pragma unroll
  for (int tt = 0; tt < 5; tt++) {
    int vt = 4 * tt + g;
    bofft[tt] = VT_OY[vt] * NCS + VT_OX[vt];
  }

  __syncthreads();

  unsigned short* fw = &featL[w * 640];
  const f32x4 zacc = {0.f, 0.f, 0.f, 0.f};

  for (int rr = 0; rr < 8; rr++) {
    int py = 8 * w + rr;
#pragma unroll
    for (int half = 0; half < 2; half++) {
      int px0 = 16 * half;
      int cbase = py * NCS + px0 + col;
      f32x4 a0 = zacc, a1 = zacc;
#pragma unroll
      for (int tt = 0; tt < 5; tt++) {
        short8 bf = *(const short8*)&ncaL[(cbase + bofft[tt]) * 8];
        a0 = __builtin_amdgcn_mfma_f32_16x16x32_bf16(wfr[2 * tt], bf, a0, 0, 0, 0);
        a1 = __builtin_amdgcn_mfma_f32_16x16x32_bf16(wfr[2 * tt + 1], bf, a1, 0, 0, 0);
      }
      unsigned p00, p01, p10, p11;
      {
        float f0 = fmaxf(a0[0] + bf0[0], 0.f), f1 = fmaxf(a0[1] + bf0[1], 0.f);
        float f2 = fmaxf(a0[2] + bf0[2], 0.f), f3 = fmaxf(a0[3] + bf0[3], 0.f);
        p00 = (unsigned)f2bf(f0) | ((unsigned)f2bf(f1) << 16);
        p01 = (unsigned)f2bf(f2) | ((unsigned)f2bf(f3) << 16);
        float h0 = fmaxf(a1[0] + bf1[0], 0.f), h1 = fmaxf(a1[1] + bf1[1], 0.f);
        float h2 = fmaxf(a1[2] + bf1[2], 0.f), h3 = fmaxf(a1[3] + bf1[3], 0.f);
        p10 = (unsigned)f2bf(h0) | ((unsigned)f2bf(h1) << 16);
        p11 = (unsigned)f2bf(h2) | ((unsigned)f2bf(h3) << 16);
      }
      uint2 wv_a; wv_a.x = p00; wv_a.y = p01;
      uint2 wv_b; wv_b.x = p10; wv_b.y = p11;
      *(uint2*)&fw[col * 40 + 4 * g] = wv_a;
      *(uint2*)&fw[col * 40 + 16 + 4 * g] = wv_b;
      short8 pf = *(const short8*)&fw[col * 40 + 8 * g];
      f32x4 hA = __builtin_amdgcn_mfma_f32_16x16x32_bf16(u1fr[0], pf, zacc, 0, 0, 0);
      f32x4 hB = __builtin_amdgcn_mfma_f32_16x16x32_bf16(u1fr[1], pf, zacc, 0, 0, 0);
      float cp = 0.f;
#pragma unroll
      for (int r = 0; r < 4; r++) {
        cp += wu2a[r] * fmaxf(hA[r] + bu1a[r], 0.f);
        cp += wu2b[r] * fmaxf(hB[r] + bu1b[r], 0.f);
      }
      cp += __shfl_xor(cp, 16);
      cp += __shfl_xor(cp, 32);
      float lastv = lastA[(size_t)b * NPIX + (size_t)(cy0 + py) * WW +
                          (cx0 + px0 + col)];
      float ov = fminf(fmaxf(lastv + bu2v + cp, 0.f), 1.f);
      if (lane < 16) outL[py * CT + px0 + col] = ov;
    }
  }

  float4 o4 = *(float4*)&outL[t * 4];
  int row = (t * 4) >> 5, colf = (t * 4) & 31;
  *(float4*)&outp[(size_t)b * NPIX + (size_t)(cy0 + row) * WW + cx0 + colf] = o4;
}

extern "C" void kernel_launch(void* const* d_in, const int* in_sizes, int n_in,
                              void* d_out, int out_size, void* d_ws,
                              size_t ws_size, hipStream_t stream) {
  const float* x = (const float*)d_in[0];
  const float* Kl = (const float*)d_in[1];
  const float* Wq = (const float*)d_in[2];
  const float* bq = (const float*)d_in[3];
  const float* Wk = (const float*)d_in[4];
  // d_in[5] = bk: softmax-invariant, unused
  const float* Wv = (const float*)d_in[6];
  const float* bv = (const float*)d_in[7];
  const float* Wp1 = (const float*)d_in[8];
  const float* bp1 = (const float*)d_in[9];
  const float* Wp2 = (const float*)d_in[10];
  const float* bp2 = (const float*)d_in[11];
  const float* alpha = (const float*)d_in[12];
  const float* Wu1 = (const float*)d_in[13];
  const float* bu1 = (const float*)d_in[14];
  const float* Wu2 = (const float*)d_in[15];
  const float* bu2 = (const float*)d_in[16];
  float* outp = (float*)d_out;

  float* ws = (float*)d_ws;
  float* lastA = ws;
  float* sA = ws + (size_t)BATCH * NPIX;
  unsigned short* apack = (unsigned short*)(ws + 2 * (size_t)BATCH * NPIX);
  unsigned short* u1pack = apack + 5120;
  float* bfu = (float*)(u1pack + 1024);

  prep_kernel<<<25, 256, 0, stream>>>(Wp1, Wp2, bp1, bp2, alpha, Wu1, apack,
                                      u1pack, bfu);

  dim3 g1(WW / 64, HH / 64, BATCH);
  stencil_kernel<<<g1, T1, 0, stream>>>(x, Kl, Wq, bq, Wk, lastA, sA);

  dim3 g2(WW / CT, HH / CT, BATCH);
  conv_kernel<<<g2, T2, 0, stream>>>(x, lastA, sA, Wv, bv, apack, u1pack, bfu,
                                     bu1, Wu2, bu2, outp);
}

// Round 4
// 104.588 us; speedup vs baseline: 5.8945x; 1.7483x over previous
//
#include <hip/hip_runtime.h>

constexpr int BATCH = 32;
constexpr int HH = 256, WW = 256;
constexpr int NPIX = HH * WW;
constexpr int STEPS = 15;
constexpr float R_C = 3.9f, EPS_C = 0.3f, BETA_C = 0.15f;
constexpr float CLAMP_LO = 1e-4f, CLAMP_HI = 1.0f - 1e-4f;

typedef __attribute__((ext_vector_type(8))) short short8;
typedef __attribute__((ext_vector_type(4))) float f32x4;

__device__ inline unsigned short f2bf(float f) {
  unsigned int u = __float_as_uint(f);
  return (unsigned short)((u + 0x7fffu + ((u >> 16) & 1u)) >> 16);
}

// Virtual-tap tables (conv): 18 real taps (9 d1 + 9 d2) + 2 zero pads,
// permuted for LDS bank phase diversity.
__constant__ int VT_OY[20] = {1,2,3,1, 3,0,0,2, 0,2,2,4, 4,4,3,2, 0,0,2,1};
__constant__ int VT_OX[20] = {3,2,3,1, 1,4,2,4, 0,2,0,2, 4,0,2,1, 1,3,3,2};
__constant__ int VT_SRC[20]= {0,0,0,0, 0,1,1,1, 1,1,1,1, 1,1,0,0, 2,2,0,0};
__constant__ int VT_TAP[20]= {2,4,8,0, 6,2,1,5, 0,4,3,7, 8,6,7,3, 0,0,5,1};

// ------------------------------------------------------------------ prep
__global__ void prep_kernel(const float* __restrict__ Wp1,
                            const float* __restrict__ Wp2,
                            const float* __restrict__ bp1,
                            const float* __restrict__ bp2,
                            const float* __restrict__ alpha,
                            const float* __restrict__ Wu1,
                            unsigned short* __restrict__ apack,
                            unsigned short* __restrict__ u1pack,
                            float* __restrict__ bfu) {
  int i = blockIdx.x * 256 + threadIdx.x;
  if (i < 5120) {
    int j = i & 7, lane = (i >> 3) & 63, tm = i >> 9;
    int mt = tm & 1;
    int o = (lane & 15) + 16 * mt, g = lane >> 4, vt = (tm >> 1) * 4 + g;
    float w = 0.f;
    if (j < 6 && VT_SRC[vt] != 2) {
      int base = o * 54 + j * 9 + VT_TAP[vt];
      w = (VT_SRC[vt] == 0) ? Wp1[base] : Wp2[base] * alpha[o];
    }
    apack[i] = f2bf(w);
  } else if (i < 6144) {
    int i2 = i - 5120;
    int j = i2 & 7, lane = (i2 >> 3) & 63, mt = i2 >> 9;
    int o = (lane & 15) + 16 * mt, g = lane >> 4;
    u1pack[i2] = f2bf(Wu1[o * 32 + 8 * g + j]);
  } else if (i < 6176) {
    int o = i - 6144;
    bfu[o] = bp1[o] + bp2[o] * alpha[o];
  }
}

// --------------------------------------------- stencil + online attention
// Band design: block owns a 256-wide x 32-row output band; region 256 x 62
// (rows 0..61 = image rows band*32-15 .. band*32+46, padded to 64 rows).
// Wave = one strip-row (64 lanes x 4 cols = 256 wide, 4 rows high): all row
// predicates are wave-uniform. g/x/softmax accum in VGPRs; LDS holds only
// `mapped`, double-buffered -> ONE barrier per step.  Horizontal zero-pad
// via LDS pad columns (no col predication).  Vertical validity cone:
// update rows [s+1, 60-s] ∩ image; tile rows 15..46 stay in-cone all steps.
constexpr int BANDH = 32;
constexpr int RROWS = 64;
constexpr int LSTR2 = 264;                 // [4 pad][256][4 pad] words
constexpr int BUFW = RROWS * LSTR2;        // 16896 words
constexpr int TS = 1024;

__global__ __launch_bounds__(TS) void stencil_kernel(
    const float* __restrict__ x, const float* __restrict__ Kl,
    const float* __restrict__ Wq, const float* __restrict__ bq,
    const float* __restrict__ Wk, float* __restrict__ lastO,
    float* __restrict__ sO) {
  extern __shared__ float sbuf[];  // 2 * BUFW floats = 135168 B

  const int band = blockIdx.x, b = blockIdx.y;
  const int gy0 = band * BANDH - 15;
  const int t = threadIdx.x;
  const int sx = t & 63, sy = t >> 6;  // wave id == strip-row
  const int c0 = 4 * sx, r0 = 4 * sy;
  const float* xim = x + (size_t)b * NPIX;

  // zero the pad columns of both buffers (1024 pad words, 1 per thread)
  {
    int bi = t >> 9, r = (t >> 3) & 63, pw = t & 7;
    sbuf[bi * BUFW + r * LSTR2 + (pw < 4 ? pw : 256 + pw)] = 0.f;
  }

  const float k00 = Kl[0], k01 = Kl[1], k02 = Kl[2];
  const float k10 = Kl[3], k11 = Kl[4], k12 = Kl[5];
  const float k20 = Kl[6], k21 = Kl[7], k22 = Kl[8];

  const float swk = Wq[0] * Wk[0] + Wq[1] * Wk[1] + Wq[2] * Wk[2];
  const float sbk = bq[0] * Wk[0] + bq[1] * Wk[1] + bq[2] * Wk[2];
  const float rs3 = 0.57735026918962576f;
  const float a1 = swk * rs3, a0c = sbk * rs3;  // score = (a1*x + a0c)*g

  const int img_lo = (gy0 < 0) ? -gy0 : 0;
  const int img_hi = (255 - gy0 < 63) ? (255 - gy0) : 63;

  float xv[4][4], g[4][4], se[4][4], ws[4][4];
#pragma unroll
  for (int rr = 0; rr < 4; rr++) {
    int ry = r0 + rr, gy = gy0 + ry;
    bool rin = (ry >= img_lo) && (ry <= img_hi);
    f32x4 v = {0.f, 0.f, 0.f, 0.f};
    if (rin) v = *(const f32x4*)&xim[gy * WW + c0];
#pragma unroll
    for (int c = 0; c < 4; c++) {
      xv[rr][c] = v[c];
      g[rr][c] = v[c];
      se[rr][c] = 0.f;
      ws[rr][c] = 0.f;
    }
  }

  const int rt = (sy == 0) ? 0 : r0 - 1;
  const int rb = (sy == 15) ? 63 : r0 + 4;

  int p = 0;
  for (int s = 0; s < STEPS; s++) {
    float* buf = sbuf + p * BUFW;
    p ^= 1;
    // mapped for own rows -> LDS (identical expression to prior rounds)
    float m[4][4];
#pragma unroll
    for (int rr = 0; rr < 4; rr++) {
      f32x4 mv;
#pragma unroll
      for (int c = 0; c < 4; c++) {
        m[rr][c] = R_C * g[rr][c] * (1.f - g[rr][c]);
        mv[c] = m[rr][c];
      }
      *(f32x4*)&buf[(r0 + rr) * LSTR2 + 4 + c0] = mv;
    }
    __syncthreads();

    // halo reads (issued up-front; TLP hides latency)
    f32x4 T4 = *(const f32x4*)&buf[rt * LSTR2 + 4 + c0];
    float TL = buf[rt * LSTR2 + 3 + c0];
    float TR = buf[rt * LSTR2 + 8 + c0];
    f32x4 B4 = *(const f32x4*)&buf[rb * LSTR2 + 4 + c0];
    float BL = buf[rb * LSTR2 + 3 + c0];
    float BR = buf[rb * LSTR2 + 8 + c0];
    float sl[4], sr[4];
#pragma unroll
    for (int rr = 0; rr < 4; rr++) {
      sl[rr] = buf[(r0 + rr) * LSTR2 + 3 + c0];
      sr[rr] = buf[(r0 + rr) * LSTR2 + 8 + c0];
    }

    // 6 window rows of 6 (halo included); SSA copies, statically indexed
    float W[6][6];
    W[0][0] = TL; W[0][1] = T4[0]; W[0][2] = T4[1];
    W[0][3] = T4[2]; W[0][4] = T4[3]; W[0][5] = TR;
#pragma unroll
    for (int rr = 0; rr < 4; rr++) {
      W[1 + rr][0] = sl[rr];
#pragma unroll
      for (int c = 0; c < 4; c++) W[1 + rr][1 + c] = m[rr][c];
      W[1 + rr][5] = sr[rr];
    }
    W[5][0] = BL; W[5][1] = B4[0]; W[5][2] = B4[1];
    W[5][3] = B4[2]; W[5][4] = B4[3]; W[5][5] = BR;

    const int ulo = (s + 1 > img_lo) ? s + 1 : img_lo;
    const int uhi = (60 - s < img_hi) ? 60 - s : img_hi;

#pragma unroll
    for (int rr = 0; rr < 4; rr++) {
      const int ry = r0 + rr;
      if (ry >= ulo && ry <= uhi) {  // wave-uniform branch
#pragma unroll
        for (int c = 0; c < 4; c++) {
          float mc = W[rr + 1][c + 1];
          float loc = k00 * W[rr][c] + k01 * W[rr][c + 1] +
                      k02 * W[rr][c + 2] + k10 * W[rr + 1][c] + k11 * mc +
                      k12 * W[rr + 1][c + 2] + k20 * W[rr + 2][c] +
                      k21 * W[rr + 2][c + 1] + k22 * W[rr + 2][c + 2];
          float ph = (1.f - EPS_C) * mc + EPS_C * loc;
          float gn = (1.f - BETA_C) * ph + BETA_C * xv[rr][c];
          g[rr][c] = fminf(fmaxf(gn, CLAMP_LO), CLAMP_HI);
        }
      }
      if (ry >= 15 && ry <= 46) {  // wave-uniform: tile rows only
#pragma unroll
        for (int c = 0; c < 4; c++) {
          float gv = g[rr][c];
          float e = __expf((a1 * xv[rr][c] + a0c) * gv);
          se[rr][c] += e;
          ws[rr][c] = fmaf(e, gv, ws[rr][c]);
        }
      }
    }
  }

#pragma unroll
  for (int rr = 0; rr < 4; rr++) {
    const int ry = r0 + rr;
    if (ry >= 15 && ry <= 46) {
      int gy = gy0 + ry;
      size_t gi = (size_t)b * NPIX + (size_t)gy * WW + c0;
      f32x4 gv, sv;
#pragma unroll
      for (int c = 0; c < 4; c++) {
        gv[c] = g[rr][c];
        sv[c] = ws[rr][c] / se[rr][c];
      }
      *(f32x4*)&lastO[gi] = gv;
      *(f32x4*)&sO[gi] = sv;
    }
  }
}

// ------------------------------------------------- conv stack via MFMA
constexpr int CT = 32;
constexpr int NR = 36, NCS = 37;
constexpr int T2 = 256;

__global__ __launch_bounds__(T2) void conv_kernel(
    const float* __restrict__ x, const float* __restrict__ lastA,
    const float* __restrict__ sA, const float* __restrict__ Wv,
    const float* __restrict__ bv, const unsigned short* __restrict__ apackG,
    const unsigned short* __restrict__ u1packG,
    const float* __restrict__ bfuG, const float* __restrict__ bu1G,
    const float* __restrict__ Wu2G, const float* __restrict__ bu2G,
    float* __restrict__ outp) {
  __shared__ __align__(16) unsigned short ncaL[NR * NCS * 8];
  __shared__ __align__(16) unsigned short featL[4 * 16 * 40];
  __shared__ __align__(16) float outL[CT * CT];

  const int cx0 = blockIdx.x * CT, cy0 = blockIdx.y * CT, b = blockIdx.z;
  const int t = threadIdx.x;
  const int w = t >> 6, lane = t & 63;
  const int g = lane >> 4, col = lane & 15;

  const float wv0 = Wv[0], wv1 = Wv[1], wv2 = Wv[2];
  const float bv0 = bv[0], bv1 = bv[1], bv2 = bv[2];
  for (int i = t; i < NR * NR; i += T2) {
    int ry = i / NR, rx = i - ry * NR;
    int gy = cy0 - 2 + ry, gx = cx0 - 2 + rx;
    unsigned short c[8];
    if (gy >= 0 && gy < HH && gx >= 0 && gx < WW) {
      size_t gi = (size_t)b * NPIX + (size_t)gy * WW + gx;
      float xvv = x[gi], lv = lastA[gi], sv = sA[gi];
      c[0] = f2bf(xvv);
      c[1] = f2bf(lv);
      c[2] = f2bf(lv - xvv);
      c[3] = f2bf(wv0 * sv + bv0);
      c[4] = f2bf(wv1 * sv + bv1);
      c[5] = f2bf(wv2 * sv + bv2);
    } else {
      c[0] = c[1] = c[2] = c[3] = c[4] = c[5] = 0;
    }
    short8 v;
    v[0] = (short)c[0]; v[1] = (short)c[1]; v[2] = (short)c[2];
    v[3] = (short)c[3]; v[4] = (short)c[4]; v[5] = (short)c[5];
    v[6] = 0; v[7] = 0;
    *(short8*)&ncaL[(ry * NCS + rx) * 8] = v;
  }

  const short8* ap = (const short8*)apackG;
  short8 wfr[10];
#pragma unroll
  for (int q = 0; q < 10; q++) wfr[q] = ap[q * 64 + lane];
  const short8* up = (const short8*)u1packG;
  short8 u1fr[2];
  u1fr[0] = up[lane];
  u1fr[1] = up[64 + lane];

  float bf0[4], bf1[4], bu1a[4], bu1b[4], wu2a[4], wu2b[4];
#pragma unroll
  for (int r = 0; r < 4; r++) {
    bf0[r] = bfuG[4 * g + r];
    bf1[r] = bfuG[16 + 4 * g + r];
    bu1a[r] = bu1G[4 * g + r];
    bu1b[r] = bu1G[16 + 4 * g + r];
    wu2a[r] = Wu2G[4 * g + r];
    wu2b[r] = Wu2G[16 + 4 * g + r];
  }
  const float bu2v = bu2G[0];

  int bofft[5];
#pragma unroll
  for (int tt = 0; tt < 5; tt++) {
    int vt = 4 * tt + g;
    bofft[tt] = VT_OY[vt] * NCS + VT_OX[vt];
  }

  __syncthreads();

  unsigned short* fw = &featL[w * 640];
  const f32x4 zacc = {0.f, 0.f, 0.f, 0.f};

  for (int rr = 0; rr < 8; rr++) {
    int py = 8 * w + rr;
#pragma unroll
    for (int half = 0; half < 2; half++) {
      int px0 = 16 * half;
      int cbase = py * NCS + px0 + col;
      f32x4 a0 = zacc, a1v = zacc;
#pragma unroll
      for (int tt = 0; tt < 5; tt++) {
        short8 bf = *(const short8*)&ncaL[(cbase + bofft[tt]) * 8];
        a0 = __builtin_amdgcn_mfma_f32_16x16x32_bf16(wfr[2 * tt], bf, a0, 0, 0, 0);
        a1v = __builtin_amdgcn_mfma_f32_16x16x32_bf16(wfr[2 * tt + 1], bf, a1v, 0, 0, 0);
      }
      unsigned p00, p01, p10, p11;
      {
        float f0 = fmaxf(a0[0] + bf0[0], 0.f), f1 = fmaxf(a0[1] + bf0[1], 0.f);
        float f2 = fmaxf(a0[2] + bf0[2], 0.f), f3 = fmaxf(a0[3] + bf0[3], 0.f);
        p00 = (unsigned)f2bf(f0) | ((unsigned)f2bf(f1) << 16);
        p01 = (unsigned)f2bf(f2) | ((unsigned)f2bf(f3) << 16);
        float h0 = fmaxf(a1v[0] + bf1[0], 0.f), h1 = fmaxf(a1v[1] + bf1[1], 0.f);
        float h2 = fmaxf(a1v[2] + bf1[2], 0.f), h3 = fmaxf(a1v[3] + bf1[3], 0.f);
        p10 = (unsigned)f2bf(h0) | ((unsigned)f2bf(h1) << 16);
        p11 = (unsigned)f2bf(h2) | ((unsigned)f2bf(h3) << 16);
      }
      uint2 wv_a; wv_a.x = p00; wv_a.y = p01;
      uint2 wv_b; wv_b.x = p10; wv_b.y = p11;
      *(uint2*)&fw[col * 40 + 4 * g] = wv_a;
      *(uint2*)&fw[col * 40 + 16 + 4 * g] = wv_b;
      short8 pf = *(const short8*)&fw[col * 40 + 8 * g];
      f32x4 hA = __builtin_amdgcn_mfma_f32_16x16x32_bf16(u1fr[0], pf, zacc, 0, 0, 0);
      f32x4 hB = __builtin_amdgcn_mfma_f32_16x16x32_bf16(u1fr[1], pf, zacc, 0, 0, 0);
      float cp = 0.f;
#pragma unroll
      for (int r = 0; r < 4; r++) {
        cp += wu2a[r] * fmaxf(hA[r] + bu1a[r], 0.f);
        cp += wu2b[r] * fmaxf(hB[r] + bu1b[r], 0.f);
      }
      cp += __shfl_xor(cp, 16);
      cp += __shfl_xor(cp, 32);
      float lastv = lastA[(size_t)b * NPIX + (size_t)(cy0 + py) * WW +
                          (cx0 + px0 + col)];
      float ov = fminf(fmaxf(lastv + bu2v + cp, 0.f), 1.f);
      if (lane < 16) outL[py * CT + px0 + col] = ov;
    }
  }

  float4 o4 = *(float4*)&outL[t * 4];
  int row = (t * 4) >> 5, colf = (t * 4) & 31;
  *(float4*)&outp[(size_t)b * NPIX + (size_t)(cy0 + row) * WW + cx0 + colf] = o4;
}

extern "C" void kernel_launch(void* const* d_in, const int* in_sizes, int n_in,
                              void* d_out, int out_size, void* d_ws,
                              size_t ws_size, hipStream_t stream) {
  const float* x = (const float*)d_in[0];
  const float* Kl = (const float*)d_in[1];
  const float* Wq = (const float*)d_in[2];
  const float* bq = (const float*)d_in[3];
  const float* Wk = (const float*)d_in[4];
  // d_in[5] = bk: softmax-invariant, unused
  const float* Wv = (const float*)d_in[6];
  const float* bv = (const float*)d_in[7];
  const float* Wp1 = (const float*)d_in[8];
  const float* bp1 = (const float*)d_in[9];
  const float* Wp2 = (const float*)d_in[10];
  const float* bp2 = (const float*)d_in[11];
  const float* alpha = (const float*)d_in[12];
  const float* Wu1 = (const float*)d_in[13];
  const float* bu1 = (const float*)d_in[14];
  const float* Wu2 = (const float*)d_in[15];
  const float* bu2 = (const float*)d_in[16];
  float* outp = (float*)d_out;

  float* ws = (float*)d_ws;
  float* lastA = ws;
  float* sA = ws + (size_t)BATCH * NPIX;
  unsigned short* apack = (unsigned short*)(ws + 2 * (size_t)BATCH * NPIX);
  unsigned short* u1pack = apack + 5120;
  float* bfu = (float*)(u1pack + 1024);

  prep_kernel<<<25, 256, 0, stream>>>(Wp1, Wp2, bp1, bp2, alpha, Wu1, apack,
                                      u1pack, bfu);

  dim3 g1(HH / BANDH, BATCH);  // 8 x 32 = 256 blocks = 1 per CU
  size_t lds1 = (size_t)2 * BUFW * sizeof(float);  // 135168 B
  stencil_kernel<<<g1, TS, lds1, stream>>>(x, Kl, Wq, bq, Wk, lastA, sA);

  dim3 g2(WW / CT, HH / CT, BATCH);
  conv_kernel<<<g2, T2, 0, stream>>>(x, lastA, sA, Wv, bv, apack, u1pack, bfu,
                                     bu1, Wu2, bu2, outp);
}